// Round 14
// baseline (184.000 us; speedup 1.0000x reference)
//
#include <hip/hip_runtime.h>
#include <hip/hip_bf16.h>
#include <hip/hip_fp16.h>

#define N_NODES 50000
#define N_EDGES 800000
#define IN_F 256
#define NH 4
#define DH 64
#define HD 256
#define ALPHA 0.2f

typedef short bf16x8 __attribute__((ext_vector_type(8)));
typedef float f32x4 __attribute__((ext_vector_type(4)));

__device__ __forceinline__ unsigned short f2bf(float f) {
    unsigned u = __float_as_uint(f);
    u = (u + 0x7FFFu + ((u >> 16) & 1u)) >> 16;   // RNE
    return (unsigned short)u;
}

// ---------------- pre: Bt transpose-convert + zero counts8 ----------------
__global__ __launch_bounds__(256) void k_pre(const float* __restrict__ fw,
                                             unsigned short* __restrict__ Bt,
                                             int* __restrict__ counts8) {
    if (blockIdx.x < 256) {
        int n = blockIdx.x;            // 0..255
        int k = threadIdx.x;           // 0..255
        Bt[n * 256 + k] = f2bf(fw[k * 256 + n]);
    } else {
        int t = (blockIdx.x - 256) * 256 + threadIdx.x;
        if (t < 2 * N_NODES) {         // 8*N_NODES ints / 4 per int4
            int4 z; z.x = 0; z.y = 0; z.z = 0; z.w = 0;
            ((int4*)counts8)[t] = z;
        }
    }
}

// ---------------- MAIN: heterogeneous blocks — even = GEMM tile, odd = histogram ----
// GEMM: BM=128, BN=256 (full), 512 thr = 8 waves (2M x 4N); B staged in TWO 64-KB
// BK=128 stages (XOR-swizzled). Swapped-operand MFMA -> direct packed f16 stores +
// in-register el/er.  HIST: 512 thr x 4 edges, rank-returning atomics -> erank.
// 64-KB LDS/block -> gemm+hist co-reside on a CU; hist latency hides under MFMA.
__global__ __launch_bounds__(512) void k_main(const float* __restrict__ A,
                                              const unsigned short* __restrict__ Bt,
                                              unsigned short* __restrict__ fth,
                                              float* __restrict__ el,
                                              float* __restrict__ er,
                                              const float* __restrict__ al,
                                              const float* __restrict__ ar,
                                              const int* __restrict__ dstv,
                                              int* __restrict__ counts8,
                                              int* __restrict__ erank, int M) {
    __shared__ __align__(16) char smem[65536];
    const int tid = threadIdx.x;

    if (blockIdx.x & 1) {
        // -------- histogram block --------
        int t = (blockIdx.x >> 1) * 512 + tid;
        if (t < N_EDGES / 4) {
            int4 d4 = *(const int4*)(dstv + t * 4);
            int cbase = (t & 7) * N_NODES;
            int4 rr;
            rr.x = atomicAdd(&counts8[cbase + d4.x], 1);
            rr.y = atomicAdd(&counts8[cbase + d4.y], 1);
            rr.z = atomicAdd(&counts8[cbase + d4.z], 1);
            rr.w = atomicAdd(&counts8[cbase + d4.w], 1);
            *(int4*)(erank + t * 4) = rr;
        }
        return;
    }

    // -------- GEMM block --------
    const int m0 = (blockIdx.x >> 1) * 128;
    const int w = tid >> 6, lane = tid & 63;
    const int wm = w >> 2, wn = w & 3;          // 2 x 4; wave's 64-col slice = head wn
    const int fr = lane & 15, quad = lane >> 4;

    const float* arow[4];
    int gm[4];
    #pragma unroll
    for (int j = 0; j < 4; j++) {
        gm[j] = m0 + wm * 64 + j * 16 + fr;
        int cr = gm[j] < M ? gm[j] : (M - 1);
        arow[j] = A + (size_t)cr * IN_F;
    }

    f32x4 acc[4][4];
    #pragma unroll
    for (int j = 0; j < 4; j++)
        #pragma unroll
        for (int f = 0; f < 4; f++) acc[j][f] = (f32x4){0.f, 0.f, 0.f, 0.f};

    #pragma unroll
    for (int h = 0; h < 2; h++) {
        if (h) __syncthreads();                 // prior stage fully consumed
        // stage B rows 0..255, k-cols [h*128, h*128+128): 64 KB
        #pragma unroll
        for (int c = 0; c < 8; c++) {
            int o = c * 8192 + tid * 16;        // linear byte offset in tile
            int n = o >> 8;                     // row
            int kb = o & 255;                   // byte within 256-B row-slice
            bf16x8 v = *(const bf16x8*)((const char*)Bt + (size_t)n * 512 + h * 256 + kb);
            int lb = o ^ (((o >> 8) & 7) << 4);
            *(bf16x8*)(smem + lb) = v;
        }
        __syncthreads();

        #pragma unroll
        for (int t = 0; t < 4; t++) {
            int kk = h * 4 + t;
            bf16x8 af[4];
            #pragma unroll
            for (int j = 0; j < 4; j++) {
                float4 lo = *(const float4*)(arow[j] + kk * 32 + quad * 8);
                float4 hi = *(const float4*)(arow[j] + kk * 32 + quad * 8 + 4);
                af[j][0] = (short)f2bf(lo.x); af[j][1] = (short)f2bf(lo.y);
                af[j][2] = (short)f2bf(lo.z); af[j][3] = (short)f2bf(lo.w);
                af[j][4] = (short)f2bf(hi.x); af[j][5] = (short)f2bf(hi.y);
                af[j][6] = (short)f2bf(hi.z); af[j][7] = (short)f2bf(hi.w);
            }
            #pragma unroll
            for (int f = 0; f < 4; f++) {
                int nl = wn * 64 + f * 16 + fr;
                int lb = (nl * 256 + t * 64 + quad * 16) ^ ((nl & 7) << 4);
                bf16x8 bfr = *(const bf16x8*)(smem + lb);
                #pragma unroll
                for (int j = 0; j < 4; j++)
                    acc[j][f] = __builtin_amdgcn_mfma_f32_16x16x32_bf16(bfr, af[j], acc[j][f], 0, 0, 0);
            }
        }
    }
    // lane holds D[row = m0+wm*64+j*16+fr][col = wn*64+f*16+quad*4+r]

    // fused el/er (head wn)
    #pragma unroll
    for (int j = 0; j < 4; j++) {
        float pl = 0.f, pr = 0.f;
        #pragma unroll
        for (int f = 0; f < 4; f++) {
            float4 a4 = *(const float4*)(al + wn * 64 + f * 16 + quad * 4);
            float4 b4 = *(const float4*)(ar + wn * 64 + f * 16 + quad * 4);
            pl += acc[j][f][0] * a4.x + acc[j][f][1] * a4.y + acc[j][f][2] * a4.z + acc[j][f][3] * a4.w;
            pr += acc[j][f][0] * b4.x + acc[j][f][1] * b4.y + acc[j][f][2] * b4.z + acc[j][f][3] * b4.w;
        }
        pl += __shfl_xor(pl, 16); pl += __shfl_xor(pl, 32);
        pr += __shfl_xor(pr, 16); pr += __shfl_xor(pr, 32);
        if (quad == 0 && gm[j] < M) {
            el[gm[j] * NH + wn] = pl;
            er[gm[j] * NH + wn] = pr;
        }
    }

    // direct f16 stores
    #pragma unroll
    for (int j = 0; j < 4; j++) {
        if (gm[j] < M) {
            unsigned short* dp = fth + (size_t)gm[j] * HD + wn * 64 + quad * 4;
            #pragma unroll
            for (int f = 0; f < 4; f++) {
                ushort4 pk;
                pk.x = __half_as_ushort(__float2half(acc[j][f][0]));
                pk.y = __half_as_ushort(__float2half(acc[j][f][1]));
                pk.z = __half_as_ushort(__float2half(acc[j][f][2]));
                pk.w = __half_as_ushort(__float2half(acc[j][f][3]));
                *(ushort4*)(dp + f * 16) = pk;
            }
        }
    }
}

// ---------------- CSR scan: merge 8 copies -> counts, per-copy exclusive prefix ----
__global__ __launch_bounds__(512) void k_scan1(int* __restrict__ counts8,
                                               int* __restrict__ counts,
                                               int* __restrict__ incl,
                                               int* __restrict__ bsum, int N) {
    __shared__ int sm[512];
    int i = blockIdx.x * 512 + threadIdx.x;
    int v = 0;
    if (i < N) {
        int pf = 0;
        #pragma unroll
        for (int c = 0; c < 8; c++) {
            int t = counts8[c * N_NODES + i];
            counts8[c * N_NODES + i] = pf;      // exclusive prefix over copies
            pf += t;
        }
        v = pf;
        counts[i] = v;
    }
    sm[threadIdx.x] = v;
    __syncthreads();
    for (int off = 1; off < 512; off <<= 1) {
        int t = (threadIdx.x >= off) ? sm[threadIdx.x - off] : 0;
        __syncthreads();
        sm[threadIdx.x] += t;
        __syncthreads();
    }
    if (i < N) incl[i] = sm[threadIdx.x];
    if (threadIdx.x == 511) bsum[blockIdx.x] = sm[511];
}

// scan3: offs[i] computed AND folded into the 8 per-copy prefixes.
__global__ __launch_bounds__(256) void k_scan3(const int* __restrict__ counts,
                                               const int* __restrict__ incl,
                                               const int* __restrict__ bsum,
                                               int* __restrict__ offs,
                                               int* __restrict__ counts8, int N) {
    __shared__ int sprefix;
    int nb = blockIdx.x >> 1;
    if (threadIdx.x < 64) {
        int v = 0;
        for (int j = threadIdx.x; j < nb; j += 64) v += bsum[j];
        #pragma unroll
        for (int off = 1; off < 64; off <<= 1) v += __shfl_xor(v, off);
        if (threadIdx.x == 0) sprefix = v;
    }
    __syncthreads();
    int i = blockIdx.x * 256 + threadIdx.x;
    if (i < N) {
        int o = incl[i] - counts[i] + sprefix;
        offs[i] = o;
        #pragma unroll
        for (int c = 0; c < 8; c++) counts8[c * N_NODES + i] += o;
    }
}

// ---------------- scatter: atomic-free, single random gather ----------------
__global__ __launch_bounds__(256) void k_scatter(const int* __restrict__ src,
                                                 const int* __restrict__ dst,
                                                 const int* __restrict__ prefix8,
                                                 const int* __restrict__ erank,
                                                 int* __restrict__ esrc) {
    int e = blockIdx.x * 256 + threadIdx.x;
    if (e < N_EDGES) {
        int d = dst[e];
        int c = (e >> 2) & 7;                    // same copy mapping as k_main hist
        int p = prefix8[c * N_NODES + d] + erank[e];
        esrc[p] = src[e];
    }
}

// ---------------- Aggregation: one wave per dst node, SINGLE PASS ----------------
__global__ __launch_bounds__(256) void k_agg(const unsigned short* __restrict__ fth,
                                             const float* __restrict__ el,
                                             const float* __restrict__ er,
                                             const int* __restrict__ offs,
                                             const int* __restrict__ counts,
                                             const int* __restrict__ esrc,
                                             float* __restrict__ out, int N) {
    int wid = (blockIdx.x * 256 + threadIdx.x) >> 6;
    const int lane = threadIdx.x & 63;
    if (wid >= N) return;
    const int deg = counts[wid];
    const int start = offs[wid];
    const int quad = lane >> 4;                 // head of my 4 cols
    const float erq = er[wid * NH + quad];

    float s = 0.f;
    float a0 = 0.f, a1 = 0.f, a2 = 0.f, a3 = 0.f;
    #pragma unroll 4
    for (int i = 0; i < deg; i++) {
        int sv = esrc[start + i];                     // wave-uniform
        float x = el[sv * NH + quad] + erq;           // 1-line broadcast gather
        x = (x > 0.f) ? x : ALPHA * x;
        float wgt = __expf(x);
        s += wgt;
        float2 raw = ((const float2*)fth)[(size_t)sv * 64 + lane];
        __half2 h0 = *reinterpret_cast<const __half2*>(&raw.x);
        __half2 h1 = *reinterpret_cast<const __half2*>(&raw.y);
        a0 = fmaf(wgt, __low2float(h0), a0);
        a1 = fmaf(wgt, __high2float(h0), a1);
        a2 = fmaf(wgt, __low2float(h1), a2);
        a3 = fmaf(wgt, __high2float(h1), a3);
    }
    float invd = (deg > 0 && s > 0.f) ? 1.f / s : 0.f;
    f32x4 o;
    o[0] = a0 * invd; o[1] = a1 * invd; o[2] = a2 * invd; o[3] = a3 * invd;
    __builtin_nontemporal_store(o, (f32x4*)out + (size_t)wid * 64 + lane);
}

// ---------------- launch ----------------
extern "C" void kernel_launch(void* const* d_in, const int* in_sizes, int n_in,
                              void* d_out, int out_size, void* d_ws, size_t ws_size,
                              hipStream_t stream) {
    const float* feat = (const float*)d_in[0];
    const float* fc_w = (const float*)d_in[1];
    const float* attn_l = (const float*)d_in[2];
    const float* attn_r = (const float*)d_in[3];
    const int* src = (const int*)d_in[4];
    const int* dst = (const int*)d_in[5];
    float* out = (float*)d_out;

    char* w = (char*)d_ws;
    unsigned short* fth = (unsigned short*)w;  w += (size_t)N_NODES * HD * 2;      // 25.6 MB (f16)
    unsigned short* Bt = (unsigned short*)w;   w += (size_t)IN_F * HD * 2;         // 128 KB (bf16)
    float* el = (float*)w;       w += (size_t)N_NODES * NH * 4;                    // 800 KB
    float* er = (float*)w;       w += (size_t)N_NODES * NH * 4;                    // 800 KB
    int* counts8 = (int*)w;      w += (size_t)8 * N_NODES * 4;                     // 1.6 MB
    int* counts = (int*)w;       w += (size_t)N_NODES * 4;
    int* incl = (int*)w;         w += (size_t)N_NODES * 4;
    int* offs = (int*)w;         w += (size_t)N_NODES * 4;
    int* bsum = (int*)w;         w += 1024;
    int* erank = (int*)w;        w += (size_t)N_EDGES * 4;                          // 3.2 MB
    int* esrc = (int*)w;         w += (size_t)N_EDGES * 4;                          // 3.2 MB

    // pre: cvt (256 blocks) + zero counts8 (391 blocks)
    k_pre<<<256 + 391, 256, 0, stream>>>(fc_w, Bt, counts8);

    // main: 391 gemm blocks (even) interleaved with 391 hist blocks (odd)
    k_main<<<782, 512, 0, stream>>>(feat, Bt, fth, el, er, attn_l, attn_r,
                                    dst, counts8, erank, N_NODES);

    int nsb = (N_NODES + 511) / 512;
    k_scan1<<<nsb, 512, 0, stream>>>(counts8, counts, incl, bsum, N_NODES);
    k_scan3<<<(N_NODES + 255) / 256, 256, 0, stream>>>(counts, incl, bsum, offs, counts8, N_NODES);

    int eblocks = (N_EDGES + 255) / 256;
    k_scatter<<<eblocks, 256, 0, stream>>>(src, dst, counts8, erank, esrc);

    int agg_blocks = (N_NODES * 64 + 255) / 256;
    k_agg<<<agg_blocks, 256, 0, stream>>>(fth, el, er, offs, counts, esrc, out, N_NODES);
}

// Round 15
// 174.634 us; speedup vs baseline: 1.0536x; 1.0536x over previous
//
#include <hip/hip_runtime.h>
#include <hip/hip_bf16.h>
#include <hip/hip_fp16.h>

#define N_NODES 50000
#define N_EDGES 800000
#define IN_F 256
#define NH 4
#define DH 64
#define HD 256
#define ALPHA 0.2f

typedef short bf16x8 __attribute__((ext_vector_type(8)));
typedef float f32x4 __attribute__((ext_vector_type(4)));

__device__ __forceinline__ unsigned short f2bf(float f) {
    unsigned u = __float_as_uint(f);
    u = (u + 0x7FFFu + ((u >> 16) & 1u)) >> 16;   // RNE
    return (unsigned short)u;
}

// ---------------- fused prep: Bt transpose-convert + dst histogram (8 copies) -------
// Heterogeneous blocks: 256 cvt blocks, then 391 hist blocks (8 edges/thread,
// 2x int4 loads, 8 independent rank-returning atomics in flight -> erank).
// Copy index: thread t owns edges t*8..t*8+7, copy c = t&7 == (e>>3)&7.
__global__ __launch_bounds__(256) void k_prep(const float* __restrict__ fw,
                                              unsigned short* __restrict__ Bt,
                                              const int* __restrict__ dstv,
                                              int* __restrict__ counts8,
                                              int* __restrict__ erank) {
    if (blockIdx.x < 256) {
        int n = blockIdx.x;            // 0..255
        int k = threadIdx.x;           // 0..255
        Bt[n * 256 + k] = f2bf(fw[k * 256 + n]);
    } else {
        int t = (blockIdx.x - 256) * 256 + threadIdx.x;
        if (t < N_EDGES / 8) {
            int4 d4a = *(const int4*)(dstv + t * 8);
            int4 d4b = *(const int4*)(dstv + t * 8 + 4);
            int cbase = (t & 7) * N_NODES;
            int4 ra, rb;
            ra.x = atomicAdd(&counts8[cbase + d4a.x], 1);
            ra.y = atomicAdd(&counts8[cbase + d4a.y], 1);
            ra.z = atomicAdd(&counts8[cbase + d4a.z], 1);
            ra.w = atomicAdd(&counts8[cbase + d4a.w], 1);
            rb.x = atomicAdd(&counts8[cbase + d4b.x], 1);
            rb.y = atomicAdd(&counts8[cbase + d4b.y], 1);
            rb.z = atomicAdd(&counts8[cbase + d4b.z], 1);
            rb.w = atomicAdd(&counts8[cbase + d4b.w], 1);
            *(int4*)(erank + t * 8) = ra;
            *(int4*)(erank + t * 8 + 4) = rb;
        }
    }
}

// ---------------- GEMM: fth = f16( feat @ fc_w ) + fused el/er ----------------
// BM=128, BN=256 (full), 512 threads = 8 waves (2M x 4N); B staged once in LDS
// (XOR-swizzled, 128 KB). Swapped-operand MFMA -> lane&15 = output ROW -> direct
// packed f16 stores + in-register el/er. One barrier total.
__global__ __launch_bounds__(512) void k_gemm(const float* __restrict__ A,
                                              const unsigned short* __restrict__ Bt,
                                              unsigned short* __restrict__ fth,
                                              float* __restrict__ el,
                                              float* __restrict__ er,
                                              const float* __restrict__ al,
                                              const float* __restrict__ ar, int M) {
    __shared__ __align__(16) char smem[131072];   // B-tile 256x256 bf16, swizzled
    const int tid = threadIdx.x;
    const int m0 = blockIdx.x * 128;

    #pragma unroll
    for (int c = 0; c < 16; c++) {
        int o = c * 8192 + tid * 16;            // byte offset
        bf16x8 v = *(const bf16x8*)((const char*)Bt + o);
        int nl = o >> 9;
        int lb = o ^ ((nl & 7) << 4);
        *(bf16x8*)(smem + lb) = v;
    }
    __syncthreads();

    const int w = tid >> 6, lane = tid & 63;
    const int wm = w >> 2, wn = w & 3;          // 2 x 4; wave's 64-col slice = head wn
    const int fr = lane & 15, quad = lane >> 4;

    const float* arow[4];
    int gm[4];
    #pragma unroll
    for (int j = 0; j < 4; j++) {
        gm[j] = m0 + wm * 64 + j * 16 + fr;
        int cr = gm[j] < M ? gm[j] : (M - 1);
        arow[j] = A + (size_t)cr * IN_F;
    }

    f32x4 acc[4][4];
    #pragma unroll
    for (int j = 0; j < 4; j++)
        #pragma unroll
        for (int f = 0; f < 4; f++) acc[j][f] = (f32x4){0.f, 0.f, 0.f, 0.f};

    #pragma unroll
    for (int kk = 0; kk < 8; kk++) {
        bf16x8 af[4];
        #pragma unroll
        for (int j = 0; j < 4; j++) {
            float4 lo = *(const float4*)(arow[j] + kk * 32 + quad * 8);
            float4 hi = *(const float4*)(arow[j] + kk * 32 + quad * 8 + 4);
            af[j][0] = (short)f2bf(lo.x); af[j][1] = (short)f2bf(lo.y);
            af[j][2] = (short)f2bf(lo.z); af[j][3] = (short)f2bf(lo.w);
            af[j][4] = (short)f2bf(hi.x); af[j][5] = (short)f2bf(hi.y);
            af[j][6] = (short)f2bf(hi.z); af[j][7] = (short)f2bf(hi.w);
        }
        #pragma unroll
        for (int f = 0; f < 4; f++) {
            int nl = wn * 64 + f * 16 + fr;
            int lb = (nl * 512 + (kk * 32 + quad * 8) * 2) ^ ((nl & 7) << 4);
            bf16x8 bfr = *(const bf16x8*)(smem + lb);
            #pragma unroll
            for (int j = 0; j < 4; j++)
                acc[j][f] = __builtin_amdgcn_mfma_f32_16x16x32_bf16(bfr, af[j], acc[j][f], 0, 0, 0);
        }
    }
    // lane holds D[row = m0+wm*64+j*16+fr][col = wn*64+f*16+quad*4+r]

    // fused el/er (head wn)
    #pragma unroll
    for (int j = 0; j < 4; j++) {
        float pl = 0.f, pr = 0.f;
        #pragma unroll
        for (int f = 0; f < 4; f++) {
            float4 a4 = *(const float4*)(al + wn * 64 + f * 16 + quad * 4);
            float4 b4 = *(const float4*)(ar + wn * 64 + f * 16 + quad * 4);
            pl += acc[j][f][0] * a4.x + acc[j][f][1] * a4.y + acc[j][f][2] * a4.z + acc[j][f][3] * a4.w;
            pr += acc[j][f][0] * b4.x + acc[j][f][1] * b4.y + acc[j][f][2] * b4.z + acc[j][f][3] * b4.w;
        }
        pl += __shfl_xor(pl, 16); pl += __shfl_xor(pl, 32);
        pr += __shfl_xor(pr, 16); pr += __shfl_xor(pr, 32);
        if (quad == 0 && gm[j] < M) {
            el[gm[j] * NH + wn] = pl;
            er[gm[j] * NH + wn] = pr;
        }
    }

    // direct f16 stores
    #pragma unroll
    for (int j = 0; j < 4; j++) {
        if (gm[j] < M) {
            unsigned short* dp = fth + (size_t)gm[j] * HD + wn * 64 + quad * 4;
            #pragma unroll
            for (int f = 0; f < 4; f++) {
                ushort4 pk;
                pk.x = __half_as_ushort(__float2half(acc[j][f][0]));
                pk.y = __half_as_ushort(__float2half(acc[j][f][1]));
                pk.z = __half_as_ushort(__float2half(acc[j][f][2]));
                pk.w = __half_as_ushort(__float2half(acc[j][f][3]));
                *(ushort4*)(dp + f * 16) = pk;
            }
        }
    }
}

// ---------------- CSR scan: merge 8 copies -> counts, per-copy exclusive prefix ----
__global__ __launch_bounds__(512) void k_scan1(int* __restrict__ counts8,
                                               int* __restrict__ counts,
                                               int* __restrict__ incl,
                                               int* __restrict__ bsum, int N) {
    __shared__ int sm[512];
    int i = blockIdx.x * 512 + threadIdx.x;
    int v = 0;
    if (i < N) {
        int pf = 0;
        #pragma unroll
        for (int c = 0; c < 8; c++) {
            int t = counts8[c * N_NODES + i];
            counts8[c * N_NODES + i] = pf;      // exclusive prefix over copies
            pf += t;
        }
        v = pf;
        counts[i] = v;
    }
    sm[threadIdx.x] = v;
    __syncthreads();
    for (int off = 1; off < 512; off <<= 1) {
        int t = (threadIdx.x >= off) ? sm[threadIdx.x - off] : 0;
        __syncthreads();
        sm[threadIdx.x] += t;
        __syncthreads();
    }
    if (i < N) incl[i] = sm[threadIdx.x];
    if (threadIdx.x == 511) bsum[blockIdx.x] = sm[511];
}

// scan3: offs[i] computed AND folded into the 8 per-copy prefixes.
__global__ __launch_bounds__(256) void k_scan3(const int* __restrict__ counts,
                                               const int* __restrict__ incl,
                                               const int* __restrict__ bsum,
                                               int* __restrict__ offs,
                                               int* __restrict__ counts8, int N) {
    __shared__ int sprefix;
    int nb = blockIdx.x >> 1;
    if (threadIdx.x < 64) {
        int v = 0;
        for (int j = threadIdx.x; j < nb; j += 64) v += bsum[j];
        #pragma unroll
        for (int off = 1; off < 64; off <<= 1) v += __shfl_xor(v, off);
        if (threadIdx.x == 0) sprefix = v;
    }
    __syncthreads();
    int i = blockIdx.x * 256 + threadIdx.x;
    if (i < N) {
        int o = incl[i] - counts[i] + sprefix;
        offs[i] = o;
        #pragma unroll
        for (int c = 0; c < 8; c++) counts8[c * N_NODES + i] += o;
    }
}

// ---------------- scatter: atomic-free, single random gather ----------------
__global__ __launch_bounds__(256) void k_scatter(const int* __restrict__ src,
                                                 const int* __restrict__ dst,
                                                 const int* __restrict__ prefix8,
                                                 const int* __restrict__ erank,
                                                 int* __restrict__ esrc) {
    int e = blockIdx.x * 256 + threadIdx.x;
    if (e < N_EDGES) {
        int d = dst[e];
        int c = (e >> 3) & 7;                    // same copy mapping as k_prep hist
        int p = prefix8[c * N_NODES + d] + erank[e];
        esrc[p] = src[e];
    }
}

// ---------------- Aggregation: one wave per dst node, SINGLE PASS ----------------
__global__ __launch_bounds__(256) void k_agg(const unsigned short* __restrict__ fth,
                                             const float* __restrict__ el,
                                             const float* __restrict__ er,
                                             const int* __restrict__ offs,
                                             const int* __restrict__ counts,
                                             const int* __restrict__ esrc,
                                             float* __restrict__ out, int N) {
    int wid = (blockIdx.x * 256 + threadIdx.x) >> 6;
    const int lane = threadIdx.x & 63;
    if (wid >= N) return;
    const int deg = counts[wid];
    const int start = offs[wid];
    const int quad = lane >> 4;                 // head of my 4 cols
    const float erq = er[wid * NH + quad];

    float s = 0.f;
    float a0 = 0.f, a1 = 0.f, a2 = 0.f, a3 = 0.f;
    #pragma unroll 8
    for (int i = 0; i < deg; i++) {
        int sv = esrc[start + i];                     // wave-uniform
        float x = el[sv * NH + quad] + erq;           // 1-line broadcast gather
        x = (x > 0.f) ? x : ALPHA * x;
        float wgt = __expf(x);
        s += wgt;
        float2 raw = ((const float2*)fth)[(size_t)sv * 64 + lane];
        __half2 h0 = *reinterpret_cast<const __half2*>(&raw.x);
        __half2 h1 = *reinterpret_cast<const __half2*>(&raw.y);
        a0 = fmaf(wgt, __low2float(h0), a0);
        a1 = fmaf(wgt, __high2float(h0), a1);
        a2 = fmaf(wgt, __low2float(h1), a2);
        a3 = fmaf(wgt, __high2float(h1), a3);
    }
    float invd = (deg > 0 && s > 0.f) ? 1.f / s : 0.f;
    f32x4 o;
    o[0] = a0 * invd; o[1] = a1 * invd; o[2] = a2 * invd; o[3] = a3 * invd;
    __builtin_nontemporal_store(o, (f32x4*)out + (size_t)wid * 64 + lane);
}

// ---------------- launch ----------------
extern "C" void kernel_launch(void* const* d_in, const int* in_sizes, int n_in,
                              void* d_out, int out_size, void* d_ws, size_t ws_size,
                              hipStream_t stream) {
    const float* feat = (const float*)d_in[0];
    const float* fc_w = (const float*)d_in[1];
    const float* attn_l = (const float*)d_in[2];
    const float* attn_r = (const float*)d_in[3];
    const int* src = (const int*)d_in[4];
    const int* dst = (const int*)d_in[5];
    float* out = (float*)d_out;

    char* w = (char*)d_ws;
    unsigned short* fth = (unsigned short*)w;  w += (size_t)N_NODES * HD * 2;      // 25.6 MB (f16)
    unsigned short* Bt = (unsigned short*)w;   w += (size_t)IN_F * HD * 2;         // 128 KB (bf16)
    float* el = (float*)w;       w += (size_t)N_NODES * NH * 4;                    // 800 KB
    float* er = (float*)w;       w += (size_t)N_NODES * NH * 4;                    // 800 KB
    int* counts8 = (int*)w;      w += (size_t)8 * N_NODES * 4;                     // 1.6 MB
    int* counts = (int*)w;       w += (size_t)N_NODES * 4;
    int* incl = (int*)w;         w += (size_t)N_NODES * 4;
    int* offs = (int*)w;         w += (size_t)N_NODES * 4;
    int* bsum = (int*)w;         w += 1024;
    int* erank = (int*)w;        w += (size_t)N_EDGES * 4;                          // 3.2 MB
    int* esrc = (int*)w;         w += (size_t)N_EDGES * 4;                          // 3.2 MB

    (void)hipMemsetAsync(counts8, 0, (size_t)8 * N_NODES * 4, stream);

    int hblocks = (N_EDGES / 8 + 255) / 256;    // 391
    k_prep<<<256 + hblocks, 256, 0, stream>>>(fc_w, Bt, dst, counts8, erank);

    k_gemm<<<(N_NODES + 127) / 128, 512, 0, stream>>>(feat, Bt, fth, el, er,
                                                      attn_l, attn_r, N_NODES);

    int nsb = (N_NODES + 511) / 512;
    k_scan1<<<nsb, 512, 0, stream>>>(counts8, counts, incl, bsum, N_NODES);
    k_scan3<<<(N_NODES + 255) / 256, 256, 0, stream>>>(counts, incl, bsum, offs, counts8, N_NODES);

    int eblocks = (N_EDGES + 255) / 256;
    k_scatter<<<eblocks, 256, 0, stream>>>(src, dst, counts8, erank, esrc);

    int agg_blocks = (N_NODES * 64 + 255) / 256;
    k_agg<<<agg_blocks, 256, 0, stream>>>(fth, el, er, offs, counts, esrc, out, N_NODES);
}

// Round 16
// 167.514 us; speedup vs baseline: 1.0984x; 1.0425x over previous
//
#include <hip/hip_runtime.h>
#include <hip/hip_bf16.h>
#include <hip/hip_fp16.h>

#define N_NODES 50000
#define N_EDGES 800000
#define IN_F 256
#define NH 4
#define DH 64
#define HD 256
#define ALPHA 0.2f
#define NCOPY 16

typedef short bf16x8 __attribute__((ext_vector_type(8)));
typedef float f32x4 __attribute__((ext_vector_type(4)));

__device__ __forceinline__ unsigned short f2bf(float f) {
    unsigned u = __float_as_uint(f);
    u = (u + 0x7FFFu + ((u >> 16) & 1u)) >> 16;   // RNE
    return (unsigned short)u;
}

// ---------------- pre: Bt transpose-convert + zero counts16 ----------------
__global__ __launch_bounds__(256) void k_pre(const float* __restrict__ fw,
                                             unsigned short* __restrict__ Bt,
                                             int* __restrict__ counts16) {
    if (blockIdx.x < 256) {
        int n = blockIdx.x;            // 0..255
        int k = threadIdx.x;           // 0..255
        Bt[n * 256 + k] = f2bf(fw[k * 256 + n]);
    } else {
        int t = (blockIdx.x - 256) * 256 + threadIdx.x;
        if (t < NCOPY * N_NODES / 4) {
            int4 z; z.x = 0; z.y = 0; z.z = 0; z.w = 0;
            ((int4*)counts16)[t] = z;
        }
    }
}

// ---------------- GEMM + embedded hist (atomics AFTER staging barrier) ----------
// BM=128, BN=256 (full), 512 threads = 8 waves (2M x 4N); B staged once in LDS
// (XOR-swizzled, 128 KB). Hist: 4 edges/thread, rank-returning atomics issued
// right after __syncthreads() -> latency drains under barrier-free MFMA+epilogue.
__global__ __launch_bounds__(512) void k_gemm(const float* __restrict__ A,
                                              const unsigned short* __restrict__ Bt,
                                              unsigned short* __restrict__ fth,
                                              float* __restrict__ el,
                                              float* __restrict__ er,
                                              const float* __restrict__ al,
                                              const float* __restrict__ ar,
                                              const int* __restrict__ dstv,
                                              int* __restrict__ counts16,
                                              int* __restrict__ erank, int M) {
    __shared__ __align__(16) char smem[131072];   // B-tile 256x256 bf16, swizzled
    const int tid = threadIdx.x;
    const int m0 = blockIdx.x * 128;

    #pragma unroll
    for (int c = 0; c < 16; c++) {
        int o = c * 8192 + tid * 16;            // byte offset
        bf16x8 v = *(const bf16x8*)((const char*)Bt + o);
        int nl = o >> 9;
        int lb = o ^ ((nl & 7) << 4);
        *(bf16x8*)(smem + lb) = v;
    }
    __syncthreads();

    // ---- embedded histogram: issue AFTER the last barrier ----
    const int gtid = blockIdx.x * 512 + tid;
    const bool do_hist = (gtid < N_EDGES / 4);
    int r0 = 0, r1 = 0, r2 = 0, r3 = 0;
    if (do_hist) {
        int4 d4 = *(const int4*)(dstv + gtid * 4);
        int cbase = (gtid & (NCOPY - 1)) * N_NODES;
        r0 = atomicAdd(&counts16[cbase + d4.x], 1);
        r1 = atomicAdd(&counts16[cbase + d4.y], 1);
        r2 = atomicAdd(&counts16[cbase + d4.z], 1);
        r3 = atomicAdd(&counts16[cbase + d4.w], 1);
    }

    const int w = tid >> 6, lane = tid & 63;
    const int wm = w >> 2, wn = w & 3;          // 2 x 4; wave's 64-col slice = head wn
    const int fr = lane & 15, quad = lane >> 4;

    const float* arow[4];
    int gm[4];
    #pragma unroll
    for (int j = 0; j < 4; j++) {
        gm[j] = m0 + wm * 64 + j * 16 + fr;
        int cr = gm[j] < M ? gm[j] : (M - 1);
        arow[j] = A + (size_t)cr * IN_F;
    }

    f32x4 acc[4][4];
    #pragma unroll
    for (int j = 0; j < 4; j++)
        #pragma unroll
        for (int f = 0; f < 4; f++) acc[j][f] = (f32x4){0.f, 0.f, 0.f, 0.f};

    #pragma unroll
    for (int kk = 0; kk < 8; kk++) {
        bf16x8 af[4];
        #pragma unroll
        for (int j = 0; j < 4; j++) {
            float4 lo = *(const float4*)(arow[j] + kk * 32 + quad * 8);
            float4 hi = *(const float4*)(arow[j] + kk * 32 + quad * 8 + 4);
            af[j][0] = (short)f2bf(lo.x); af[j][1] = (short)f2bf(lo.y);
            af[j][2] = (short)f2bf(lo.z); af[j][3] = (short)f2bf(lo.w);
            af[j][4] = (short)f2bf(hi.x); af[j][5] = (short)f2bf(hi.y);
            af[j][6] = (short)f2bf(hi.z); af[j][7] = (short)f2bf(hi.w);
        }
        #pragma unroll
        for (int f = 0; f < 4; f++) {
            int nl = wn * 64 + f * 16 + fr;
            int lb = (nl * 512 + (kk * 32 + quad * 8) * 2) ^ ((nl & 7) << 4);
            bf16x8 bfr = *(const bf16x8*)(smem + lb);
            #pragma unroll
            for (int j = 0; j < 4; j++)
                acc[j][f] = __builtin_amdgcn_mfma_f32_16x16x32_bf16(bfr, af[j], acc[j][f], 0, 0, 0);
        }
    }
    // lane holds D[row = m0+wm*64+j*16+fr][col = wn*64+f*16+quad*4+r]

    // fused el/er (head wn)
    #pragma unroll
    for (int j = 0; j < 4; j++) {
        float pl = 0.f, pr = 0.f;
        #pragma unroll
        for (int f = 0; f < 4; f++) {
            float4 a4 = *(const float4*)(al + wn * 64 + f * 16 + quad * 4);
            float4 b4 = *(const float4*)(ar + wn * 64 + f * 16 + quad * 4);
            pl += acc[j][f][0] * a4.x + acc[j][f][1] * a4.y + acc[j][f][2] * a4.z + acc[j][f][3] * a4.w;
            pr += acc[j][f][0] * b4.x + acc[j][f][1] * b4.y + acc[j][f][2] * b4.z + acc[j][f][3] * b4.w;
        }
        pl += __shfl_xor(pl, 16); pl += __shfl_xor(pl, 32);
        pr += __shfl_xor(pr, 16); pr += __shfl_xor(pr, 32);
        if (quad == 0 && gm[j] < M) {
            el[gm[j] * NH + wn] = pl;
            er[gm[j] * NH + wn] = pr;
        }
    }

    // direct f16 stores
    #pragma unroll
    for (int j = 0; j < 4; j++) {
        if (gm[j] < M) {
            unsigned short* dp = fth + (size_t)gm[j] * HD + wn * 64 + quad * 4;
            #pragma unroll
            for (int f = 0; f < 4; f++) {
                ushort4 pk;
                pk.x = __half_as_ushort(__float2half(acc[j][f][0]));
                pk.y = __half_as_ushort(__float2half(acc[j][f][1]));
                pk.z = __half_as_ushort(__float2half(acc[j][f][2]));
                pk.w = __half_as_ushort(__float2half(acc[j][f][3]));
                *(ushort4*)(dp + f * 16) = pk;
            }
        }
    }

    // hist ranks written last: the only wait on the atomic returns
    if (do_hist) {
        int4 rr; rr.x = r0; rr.y = r1; rr.z = r2; rr.w = r3;
        *(int4*)(erank + gtid * 4) = rr;
    }
}

// ---------------- CSR scan: merge 16 copies -> counts, per-copy exclusive prefix ----
__global__ __launch_bounds__(512) void k_scan1(int* __restrict__ counts16,
                                               int* __restrict__ counts,
                                               int* __restrict__ incl,
                                               int* __restrict__ bsum, int N) {
    __shared__ int sm[512];
    int i = blockIdx.x * 512 + threadIdx.x;
    int v = 0;
    if (i < N) {
        int pf = 0;
        #pragma unroll
        for (int c = 0; c < NCOPY; c++) {
            int t = counts16[c * N_NODES + i];
            counts16[c * N_NODES + i] = pf;     // exclusive prefix over copies
            pf += t;
        }
        v = pf;
        counts[i] = v;
    }
    sm[threadIdx.x] = v;
    __syncthreads();
    for (int off = 1; off < 512; off <<= 1) {
        int t = (threadIdx.x >= off) ? sm[threadIdx.x - off] : 0;
        __syncthreads();
        sm[threadIdx.x] += t;
        __syncthreads();
    }
    if (i < N) incl[i] = sm[threadIdx.x];
    if (threadIdx.x == 511) bsum[blockIdx.x] = sm[511];
}

// scan3: offs[i] computed AND folded into the 16 per-copy prefixes.
__global__ __launch_bounds__(256) void k_scan3(const int* __restrict__ counts,
                                               const int* __restrict__ incl,
                                               const int* __restrict__ bsum,
                                               int* __restrict__ offs,
                                               int* __restrict__ counts16, int N) {
    __shared__ int sprefix;
    int nb = blockIdx.x >> 1;
    if (threadIdx.x < 64) {
        int v = 0;
        for (int j = threadIdx.x; j < nb; j += 64) v += bsum[j];
        #pragma unroll
        for (int off = 1; off < 64; off <<= 1) v += __shfl_xor(v, off);
        if (threadIdx.x == 0) sprefix = v;
    }
    __syncthreads();
    int i = blockIdx.x * 256 + threadIdx.x;
    if (i < N) {
        int o = incl[i] - counts[i] + sprefix;
        offs[i] = o;
        #pragma unroll
        for (int c = 0; c < NCOPY; c++) counts16[c * N_NODES + i] += o;
    }
}

// ---------------- scatter: atomic-free, single random gather ----------------
__global__ __launch_bounds__(256) void k_scatter(const int* __restrict__ src,
                                                 const int* __restrict__ dst,
                                                 const int* __restrict__ prefix16,
                                                 const int* __restrict__ erank,
                                                 int* __restrict__ esrc) {
    int e = blockIdx.x * 256 + threadIdx.x;
    if (e < N_EDGES) {
        int d = dst[e];
        int c = (e >> 2) & (NCOPY - 1);          // same copy mapping as k_gemm hist
        int p = prefix16[c * N_NODES + d] + erank[e];
        esrc[p] = src[e];
    }
}

// ---------------- Aggregation: one wave per dst node, SINGLE PASS ----------------
__global__ __launch_bounds__(256) void k_agg(const unsigned short* __restrict__ fth,
                                             const float* __restrict__ el,
                                             const float* __restrict__ er,
                                             const int* __restrict__ offs,
                                             const int* __restrict__ counts,
                                             const int* __restrict__ esrc,
                                             float* __restrict__ out, int N) {
    int wid = (blockIdx.x * 256 + threadIdx.x) >> 6;
    const int lane = threadIdx.x & 63;
    if (wid >= N) return;
    const int deg = counts[wid];
    const int start = offs[wid];
    const int quad = lane >> 4;                 // head of my 4 cols
    const float erq = er[wid * NH + quad];

    float s = 0.f;
    float a0 = 0.f, a1 = 0.f, a2 = 0.f, a3 = 0.f;
    #pragma unroll 4
    for (int i = 0; i < deg; i++) {
        int sv = esrc[start + i];                     // wave-uniform
        float x = el[sv * NH + quad] + erq;           // 1-line broadcast gather
        x = (x > 0.f) ? x : ALPHA * x;
        float wgt = __expf(x);
        s += wgt;
        float2 raw = ((const float2*)fth)[(size_t)sv * 64 + lane];
        __half2 h0 = *reinterpret_cast<const __half2*>(&raw.x);
        __half2 h1 = *reinterpret_cast<const __half2*>(&raw.y);
        a0 = fmaf(wgt, __low2float(h0), a0);
        a1 = fmaf(wgt, __high2float(h0), a1);
        a2 = fmaf(wgt, __low2float(h1), a2);
        a3 = fmaf(wgt, __high2float(h1), a3);
    }
    float invd = (deg > 0 && s > 0.f) ? 1.f / s : 0.f;
    f32x4 o;
    o[0] = a0 * invd; o[1] = a1 * invd; o[2] = a2 * invd; o[3] = a3 * invd;
    __builtin_nontemporal_store(o, (f32x4*)out + (size_t)wid * 64 + lane);
}

// ---------------- launch ----------------
extern "C" void kernel_launch(void* const* d_in, const int* in_sizes, int n_in,
                              void* d_out, int out_size, void* d_ws, size_t ws_size,
                              hipStream_t stream) {
    const float* feat = (const float*)d_in[0];
    const float* fc_w = (const float*)d_in[1];
    const float* attn_l = (const float*)d_in[2];
    const float* attn_r = (const float*)d_in[3];
    const int* src = (const int*)d_in[4];
    const int* dst = (const int*)d_in[5];
    float* out = (float*)d_out;

    char* w = (char*)d_ws;
    unsigned short* fth = (unsigned short*)w;  w += (size_t)N_NODES * HD * 2;      // 25.6 MB (f16)
    unsigned short* Bt = (unsigned short*)w;   w += (size_t)IN_F * HD * 2;         // 128 KB (bf16)
    float* el = (float*)w;       w += (size_t)N_NODES * NH * 4;                    // 800 KB
    float* er = (float*)w;       w += (size_t)N_NODES * NH * 4;                    // 800 KB
    int* counts16 = (int*)w;     w += (size_t)NCOPY * N_NODES * 4;                 // 3.2 MB
    int* counts = (int*)w;       w += (size_t)N_NODES * 4;
    int* incl = (int*)w;         w += (size_t)N_NODES * 4;
    int* offs = (int*)w;         w += (size_t)N_NODES * 4;
    int* bsum = (int*)w;         w += 1024;
    int* erank = (int*)w;        w += (size_t)N_EDGES * 4;                          // 3.2 MB
    int* esrc = (int*)w;         w += (size_t)N_EDGES * 4;                          // 3.2 MB

    // pre: cvt (256 blocks) + zero counts16 (782 blocks)
    int zblocks = (NCOPY * N_NODES / 4 + 255) / 256;
    k_pre<<<256 + zblocks, 256, 0, stream>>>(fc_w, Bt, counts16);

    k_gemm<<<(N_NODES + 127) / 128, 512, 0, stream>>>(feat, Bt, fth, el, er,
                                                      attn_l, attn_r,
                                                      dst, counts16, erank, N_NODES);

    int nsb = (N_NODES + 511) / 512;
    k_scan1<<<nsb, 512, 0, stream>>>(counts16, counts, incl, bsum, N_NODES);
    k_scan3<<<(N_NODES + 255) / 256, 256, 0, stream>>>(counts, incl, bsum, offs, counts16, N_NODES);

    int eblocks = (N_EDGES + 255) / 256;
    k_scatter<<<eblocks, 256, 0, stream>>>(src, dst, counts16, erank, esrc);

    int agg_blocks = (N_NODES * 64 + 255) / 256;
    k_agg<<<agg_blocks, 256, 0, stream>>>(fth, el, er, offs, counts, esrc, out, N_NODES);
}

// Round 17
// 164.507 us; speedup vs baseline: 1.1185x; 1.0183x over previous
//
#include <hip/hip_runtime.h>
#include <hip/hip_bf16.h>
#include <hip/hip_fp16.h>

#define N_NODES 50000
#define N_EDGES 800000
#define IN_F 256
#define NH 4
#define DH 64
#define HD 256
#define ALPHA 0.2f
#define NCOPY 16

typedef short bf16x8 __attribute__((ext_vector_type(8)));
typedef float f32x4 __attribute__((ext_vector_type(4)));

__device__ __forceinline__ unsigned short f2bf(float f) {
    unsigned u = __float_as_uint(f);
    u = (u + 0x7FFFu + ((u >> 16) & 1u)) >> 16;   // RNE
    return (unsigned short)u;
}

// ---------------- pre: Bt transpose-convert + zero counts16 ----------------
__global__ __launch_bounds__(256) void k_pre(const float* __restrict__ fw,
                                             unsigned short* __restrict__ Bt,
                                             int* __restrict__ counts16) {
    if (blockIdx.x < 256) {
        int n = blockIdx.x;            // 0..255
        int k = threadIdx.x;           // 0..255
        Bt[n * 256 + k] = f2bf(fw[k * 256 + n]);
    } else {
        int t = (blockIdx.x - 256) * 256 + threadIdx.x;
        if (t < NCOPY * N_NODES / 4) {
            int4 z; z.x = 0; z.y = 0; z.z = 0; z.w = 0;
            ((int4*)counts16)[t] = z;
        }
    }
}

// ---------------- GEMM + embedded hist (XCD-local copies, atomics after barrier) ----
// BM=128, BN=256 (full), 512 threads = 8 waves (2M x 4N); B staged once in LDS
// (XOR-swizzled, 128 KB). Hist: 4 edges/thread; copy = (bid&7)*2+(tid>>8) so each
// copy's 200 KB is only touched by one XCD's blocks -> L2-local RMW, no cross-XCD
// line migration. Rank-returning atomics issued after __syncthreads(); the drain
// hides under barrier-free MFMA+epilogue.
__global__ __launch_bounds__(512) void k_gemm(const float* __restrict__ A,
                                              const unsigned short* __restrict__ Bt,
                                              unsigned short* __restrict__ fth,
                                              float* __restrict__ el,
                                              float* __restrict__ er,
                                              const float* __restrict__ al,
                                              const float* __restrict__ ar,
                                              const int* __restrict__ dstv,
                                              int* __restrict__ counts16,
                                              int* __restrict__ erank, int M) {
    __shared__ __align__(16) char smem[131072];   // B-tile 256x256 bf16, swizzled
    const int tid = threadIdx.x;
    const int m0 = blockIdx.x * 128;

    #pragma unroll
    for (int c = 0; c < 16; c++) {
        int o = c * 8192 + tid * 16;            // byte offset
        bf16x8 v = *(const bf16x8*)((const char*)Bt + o);
        int nl = o >> 9;
        int lb = o ^ ((nl & 7) << 4);
        *(bf16x8*)(smem + lb) = v;
    }
    __syncthreads();

    // ---- embedded histogram: issue AFTER the last barrier, XCD-local copy ----
    const int gtid = blockIdx.x * 512 + tid;
    const bool do_hist = (gtid < N_EDGES / 4);
    int r0 = 0, r1 = 0, r2 = 0, r3 = 0;
    if (do_hist) {
        int4 d4 = *(const int4*)(dstv + gtid * 4);
        int cbase = ((blockIdx.x & 7) * 2 + (tid >> 8)) * N_NODES;
        r0 = atomicAdd(&counts16[cbase + d4.x], 1);
        r1 = atomicAdd(&counts16[cbase + d4.y], 1);
        r2 = atomicAdd(&counts16[cbase + d4.z], 1);
        r3 = atomicAdd(&counts16[cbase + d4.w], 1);
    }

    const int w = tid >> 6, lane = tid & 63;
    const int wm = w >> 2, wn = w & 3;          // 2 x 4; wave's 64-col slice = head wn
    const int fr = lane & 15, quad = lane >> 4;

    const float* arow[4];
    int gm[4];
    #pragma unroll
    for (int j = 0; j < 4; j++) {
        gm[j] = m0 + wm * 64 + j * 16 + fr;
        int cr = gm[j] < M ? gm[j] : (M - 1);
        arow[j] = A + (size_t)cr * IN_F;
    }

    f32x4 acc[4][4];
    #pragma unroll
    for (int j = 0; j < 4; j++)
        #pragma unroll
        for (int f = 0; f < 4; f++) acc[j][f] = (f32x4){0.f, 0.f, 0.f, 0.f};

    #pragma unroll
    for (int kk = 0; kk < 8; kk++) {
        bf16x8 af[4];
        #pragma unroll
        for (int j = 0; j < 4; j++) {
            float4 lo = *(const float4*)(arow[j] + kk * 32 + quad * 8);
            float4 hi = *(const float4*)(arow[j] + kk * 32 + quad * 8 + 4);
            af[j][0] = (short)f2bf(lo.x); af[j][1] = (short)f2bf(lo.y);
            af[j][2] = (short)f2bf(lo.z); af[j][3] = (short)f2bf(lo.w);
            af[j][4] = (short)f2bf(hi.x); af[j][5] = (short)f2bf(hi.y);
            af[j][6] = (short)f2bf(hi.z); af[j][7] = (short)f2bf(hi.w);
        }
        #pragma unroll
        for (int f = 0; f < 4; f++) {
            int nl = wn * 64 + f * 16 + fr;
            int lb = (nl * 512 + (kk * 32 + quad * 8) * 2) ^ ((nl & 7) << 4);
            bf16x8 bfr = *(const bf16x8*)(smem + lb);
            #pragma unroll
            for (int j = 0; j < 4; j++)
                acc[j][f] = __builtin_amdgcn_mfma_f32_16x16x32_bf16(bfr, af[j], acc[j][f], 0, 0, 0);
        }
    }
    // lane holds D[row = m0+wm*64+j*16+fr][col = wn*64+f*16+quad*4+r]

    // fused el/er (head wn)
    #pragma unroll
    for (int j = 0; j < 4; j++) {
        float pl = 0.f, pr = 0.f;
        #pragma unroll
        for (int f = 0; f < 4; f++) {
            float4 a4 = *(const float4*)(al + wn * 64 + f * 16 + quad * 4);
            float4 b4 = *(const float4*)(ar + wn * 64 + f * 16 + quad * 4);
            pl += acc[j][f][0] * a4.x + acc[j][f][1] * a4.y + acc[j][f][2] * a4.z + acc[j][f][3] * a4.w;
            pr += acc[j][f][0] * b4.x + acc[j][f][1] * b4.y + acc[j][f][2] * b4.z + acc[j][f][3] * b4.w;
        }
        pl += __shfl_xor(pl, 16); pl += __shfl_xor(pl, 32);
        pr += __shfl_xor(pr, 16); pr += __shfl_xor(pr, 32);
        if (quad == 0 && gm[j] < M) {
            el[gm[j] * NH + wn] = pl;
            er[gm[j] * NH + wn] = pr;
        }
    }

    // direct f16 stores
    #pragma unroll
    for (int j = 0; j < 4; j++) {
        if (gm[j] < M) {
            unsigned short* dp = fth + (size_t)gm[j] * HD + wn * 64 + quad * 4;
            #pragma unroll
            for (int f = 0; f < 4; f++) {
                ushort4 pk;
                pk.x = __half_as_ushort(__float2half(acc[j][f][0]));
                pk.y = __half_as_ushort(__float2half(acc[j][f][1]));
                pk.z = __half_as_ushort(__float2half(acc[j][f][2]));
                pk.w = __half_as_ushort(__float2half(acc[j][f][3]));
                *(ushort4*)(dp + f * 16) = pk;
            }
        }
    }

    // hist ranks written last: the only wait on the atomic returns
    if (do_hist) {
        int4 rr; rr.x = r0; rr.y = r1; rr.z = r2; rr.w = r3;
        *(int4*)(erank + gtid * 4) = rr;
    }
}

// ---------------- CSR scan: merge 16 copies -> counts, per-copy exclusive prefix ----
__global__ __launch_bounds__(512) void k_scan1(int* __restrict__ counts16,
                                               int* __restrict__ counts,
                                               int* __restrict__ incl,
                                               int* __restrict__ bsum, int N) {
    __shared__ int sm[512];
    int i = blockIdx.x * 512 + threadIdx.x;
    int v = 0;
    if (i < N) {
        int pf = 0;
        #pragma unroll
        for (int c = 0; c < NCOPY; c++) {
            int t = counts16[c * N_NODES + i];
            counts16[c * N_NODES + i] = pf;     // exclusive prefix over copies
            pf += t;
        }
        v = pf;
        counts[i] = v;
    }
    sm[threadIdx.x] = v;
    __syncthreads();
    for (int off = 1; off < 512; off <<= 1) {
        int t = (threadIdx.x >= off) ? sm[threadIdx.x - off] : 0;
        __syncthreads();
        sm[threadIdx.x] += t;
        __syncthreads();
    }
    if (i < N) incl[i] = sm[threadIdx.x];
    if (threadIdx.x == 511) bsum[blockIdx.x] = sm[511];
}

// scan3: offs[i] computed AND folded into the 16 per-copy prefixes.
__global__ __launch_bounds__(256) void k_scan3(const int* __restrict__ counts,
                                               const int* __restrict__ incl,
                                               const int* __restrict__ bsum,
                                               int* __restrict__ offs,
                                               int* __restrict__ counts16, int N) {
    __shared__ int sprefix;
    int nb = blockIdx.x >> 1;
    if (threadIdx.x < 64) {
        int v = 0;
        for (int j = threadIdx.x; j < nb; j += 64) v += bsum[j];
        #pragma unroll
        for (int off = 1; off < 64; off <<= 1) v += __shfl_xor(v, off);
        if (threadIdx.x == 0) sprefix = v;
    }
    __syncthreads();
    int i = blockIdx.x * 256 + threadIdx.x;
    if (i < N) {
        int o = incl[i] - counts[i] + sprefix;
        offs[i] = o;
        #pragma unroll
        for (int c = 0; c < NCOPY; c++) counts16[c * N_NODES + i] += o;
    }
}

// ---------------- scatter: atomic-free, single random gather ----------------
__global__ __launch_bounds__(256) void k_scatter(const int* __restrict__ src,
                                                 const int* __restrict__ dst,
                                                 const int* __restrict__ prefix16,
                                                 const int* __restrict__ erank,
                                                 int* __restrict__ esrc) {
    int e = blockIdx.x * 256 + threadIdx.x;
    if (e < N_EDGES) {
        int d = dst[e];
        // reconstruct k_gemm's copy: gtid=e>>2, bid=gtid>>9, hi=(gtid>>8)&1
        int c = ((e >> 11) & 7) * 2 + ((e >> 10) & 1);
        int p = prefix16[c * N_NODES + d] + erank[e];
        esrc[p] = src[e];
    }
}

// ---------------- Aggregation: one wave per dst node, SINGLE PASS ----------------
__global__ __launch_bounds__(256) void k_agg(const unsigned short* __restrict__ fth,
                                             const float* __restrict__ el,
                                             const float* __restrict__ er,
                                             const int* __restrict__ offs,
                                             const int* __restrict__ counts,
                                             const int* __restrict__ esrc,
                                             float* __restrict__ out, int N) {
    int wid = (blockIdx.x * 256 + threadIdx.x) >> 6;
    const int lane = threadIdx.x & 63;
    if (wid >= N) return;
    const int deg = counts[wid];
    const int start = offs[wid];
    const int quad = lane >> 4;                 // head of my 4 cols
    const float erq = er[wid * NH + quad];

    float s = 0.f;
    float a0 = 0.f, a1 = 0.f, a2 = 0.f, a3 = 0.f;
    #pragma unroll 4
    for (int i = 0; i < deg; i++) {
        int sv = esrc[start + i];                     // wave-uniform
        float x = el[sv * NH + quad] + erq;           // 1-line broadcast gather
        x = (x > 0.f) ? x : ALPHA * x;
        float wgt = __expf(x);
        s += wgt;
        float2 raw = ((const float2*)fth)[(size_t)sv * 64 + lane];
        __half2 h0 = *reinterpret_cast<const __half2*>(&raw.x);
        __half2 h1 = *reinterpret_cast<const __half2*>(&raw.y);
        a0 = fmaf(wgt, __low2float(h0), a0);
        a1 = fmaf(wgt, __high2float(h0), a1);
        a2 = fmaf(wgt, __low2float(h1), a2);
        a3 = fmaf(wgt, __high2float(h1), a3);
    }
    float invd = (deg > 0 && s > 0.f) ? 1.f / s : 0.f;
    f32x4 o;
    o[0] = a0 * invd; o[1] = a1 * invd; o[2] = a2 * invd; o[3] = a3 * invd;
    __builtin_nontemporal_store(o, (f32x4*)out + (size_t)wid * 64 + lane);
}

// ---------------- launch ----------------
extern "C" void kernel_launch(void* const* d_in, const int* in_sizes, int n_in,
                              void* d_out, int out_size, void* d_ws, size_t ws_size,
                              hipStream_t stream) {
    const float* feat = (const float*)d_in[0];
    const float* fc_w = (const float*)d_in[1];
    const float* attn_l = (const float*)d_in[2];
    const float* attn_r = (const float*)d_in[3];
    const int* src = (const int*)d_in[4];
    const int* dst = (const int*)d_in[5];
    float* out = (float*)d_out;

    char* w = (char*)d_ws;
    unsigned short* fth = (unsigned short*)w;  w += (size_t)N_NODES * HD * 2;      // 25.6 MB (f16)
    unsigned short* Bt = (unsigned short*)w;   w += (size_t)IN_F * HD * 2;         // 128 KB (bf16)
    float* el = (float*)w;       w += (size_t)N_NODES * NH * 4;                    // 800 KB
    float* er = (float*)w;       w += (size_t)N_NODES * NH * 4;                    // 800 KB
    int* counts16 = (int*)w;     w += (size_t)NCOPY * N_NODES * 4;                 // 3.2 MB
    int* counts = (int*)w;       w += (size_t)N_NODES * 4;
    int* incl = (int*)w;         w += (size_t)N_NODES * 4;
    int* offs = (int*)w;         w += (size_t)N_NODES * 4;
    int* bsum = (int*)w;         w += 1024;
    int* erank = (int*)w;        w += (size_t)N_EDGES * 4;                          // 3.2 MB
    int* esrc = (int*)w;         w += (size_t)N_EDGES * 4;                          // 3.2 MB

    // pre: cvt (256 blocks) + zero counts16 (782 blocks)
    int zblocks = (NCOPY * N_NODES / 4 + 255) / 256;
    k_pre<<<256 + zblocks, 256, 0, stream>>>(fc_w, Bt, counts16);

    k_gemm<<<(N_NODES + 127) / 128, 512, 0, stream>>>(feat, Bt, fth, el, er,
                                                      attn_l, attn_r,
                                                      dst, counts16, erank, N_NODES);

    int nsb = (N_NODES + 511) / 512;
    k_scan1<<<nsb, 512, 0, stream>>>(counts16, counts, incl, bsum, N_NODES);
    k_scan3<<<(N_NODES + 255) / 256, 256, 0, stream>>>(counts, incl, bsum, offs, counts16, N_NODES);

    int eblocks = (N_EDGES + 255) / 256;
    k_scatter<<<eblocks, 256, 0, stream>>>(src, dst, counts16, erank, esrc);

    int agg_blocks = (N_NODES * 64 + 255) / 256;
    k_agg<<<agg_blocks, 256, 0, stream>>>(fth, el, er, offs, counts, esrc, out, N_NODES);
}